// Round 12
// baseline (231.186 us; speedup 1.0000x reference)
//
#include <hip/hip_runtime.h>
#include <hip/hip_bf16.h>

// CumulativeLayerNorm fused single-pass v12: x [B=8, C=512, T=16000] f32.
// TCH=320 => 50 chunks/batch, grid = 400 blocks x 512 thr, ALL co-resident
// (2-3 blocks/CU). Global phase alignment: all phase A first (streams x into
// L3 — x is 250MiB and FITS the 256MiB L3), short phase B (chains=50 => ONE
// 64-lane lookback slice, publish + single spin round per quantity), then all
// phase C re-reads from L3 and nt-stores out.
// Workspace: W1[B*50] + W2[B*50] u64 {flag|f32} (memset 0 each launch).

constexpr int Bb = 8;
constexpr int Cc = 512;
constexpr int Tt = 16000;
constexpr int T4 = Tt / 4;          // 4000
constexpr int TCH = 320;            // t per chunk
constexpr int T4CH = TCH / 4;       // 80
constexpr int NCHK = Tt / TCH;      // 50
constexpr float EPSF = 1e-8f;

typedef float f32x4 __attribute__((ext_vector_type(4)));

__device__ __forceinline__ unsigned long long pack_av(float v) {
    return (1ull << 32) | (unsigned long long)__float_as_uint(v);
}

__device__ __forceinline__ f32x4 shflx(f32x4 v, int m) {
    f32x4 r;
    r.x = __shfl_xor(v.x, m, 64);
    r.y = __shfl_xor(v.y, m, 64);
    r.z = __shfl_xor(v.z, m, 64);
    r.w = __shfl_xor(v.w, m, 64);
    return r;
}

__device__ __forceinline__ float spin_load(const unsigned long long* p) {
    unsigned long long w;
    for (;;) {
        w = __hip_atomic_load(p, __ATOMIC_RELAXED, __HIP_MEMORY_SCOPE_AGENT);
        if (w >> 32) break;
        __builtin_amdgcn_s_sleep(1);
    }
    return __uint_as_float((unsigned)w);
}

__global__ __launch_bounds__(512, 6)
void fused_cln_kernel(const float* __restrict__ x,
                      const float* __restrict__ gamma,
                      const float* __restrict__ beta,
                      float* __restrict__ out,
                      unsigned long long* __restrict__ W1,
                      unsigned long long* __restrict__ W2)
{
    const int bid = blockIdx.x;
    const int k = bid >> 3;          // chunk 0..49 (k-major: chains advance together)
    const int b = bid & 7;
    const int tid = threadIdx.x;
    const int lane = tid & 63;
    const int wave = tid >> 6;       // 0..7
    const int c_sub = tid >> 4;      // 0..31 (16 channels each: c = c_sub + 32r)
    const int t4s   = tid & 15;      // 0..15 (5 positions each: p = 16g + t4s)
    const float Cf = (float)Cc;

    __shared__ f32x4 red_s[8][T4CH], red_q[8][T4CH];   // 20 KB
    __shared__ f32x4 mean_l[T4CH], istd_l[T4CH];       // 2.5 KB
    __shared__ float gam[Cc], bet[Cc];                 // 4 KB

    gam[tid] = gamma[tid];
    bet[tid] = beta[tid];

    const f32x4* xbase = (const f32x4*)x + (size_t)(b * Cc + c_sub) * T4 + k * T4CH + t4s;

    // ---------- phase A: stream tile, per-(g,t4s) column partial sums ----------
    f32x4 ps[5] = {0, 0, 0, 0, 0};
    f32x4 pq[5] = {0, 0, 0, 0, 0};
    #pragma unroll
    for (int r = 0; r < 16; ++r) {
        #pragma unroll
        for (int g = 0; g < 5; ++g) {
            const f32x4 v = xbase[(size_t)(32 * r) * T4 + 16 * g];
            ps[g] += v;
            pq[g] += v * v;
        }
    }
    // fold the wave's 4 c_sub groups (lane bits 4,5)
    #pragma unroll
    for (int g = 0; g < 5; ++g) {
        ps[g] += shflx(ps[g], 16); pq[g] += shflx(pq[g], 16);
        ps[g] += shflx(ps[g], 32); pq[g] += shflx(pq[g], 32);
    }
    if (lane < 16) {
        #pragma unroll
        for (int g = 0; g < 5; ++g) {
            red_s[wave][g * 16 + lane] = ps[g];
            red_q[wave][g * 16 + lane] = pq[g];
        }
    }
    __syncthreads();

    // ---------- phase B: wave 0 — scan 320 t's (2 passes) + 1-slice lookbacks ----------
    if (tid < 64) {
        const int chain = b * NCHK;

        // gather: pass1 positions p=lane (64), pass2 p=64+lane (lane<16)
        f32x4 svA = 0, qvA = 0, svB = 0, qvB = 0;
        #pragma unroll
        for (int w = 0; w < 8; ++w) { svA += red_s[w][lane]; qvA += red_q[w][lane]; }
        if (lane < 16) {
            #pragma unroll
            for (int w = 0; w < 8; ++w) { svB += red_s[w][64 + lane]; qvB += red_q[w][64 + lane]; }
        }

        // ---- s1 scan, pass1 ----
        const float a0 = svA.x, a1 = a0 + svA.y, a2 = a1 + svA.z, a3 = a2 + svA.w;
        float sA = a3;
        #pragma unroll
        for (int off = 1; off < 64; off <<= 1) {
            const float n = __shfl_up(sA, off, 64);
            if (lane >= off) sA += n;
        }
        const float TP1 = __shfl(sA, 63, 64);
        const float exA = sA - a3;
        // ---- s1 scan, pass2 (16 lanes) ----
        const float e0 = svB.x, e1 = e0 + svB.y, e2 = e1 + svB.z, e3 = e2 + svB.w;
        float sB = (lane < 16) ? e3 : 0.f;
        const float lsB = sB;
        #pragma unroll
        for (int off = 1; off < 16; off <<= 1) {
            const float n = __shfl_up(sB, off, 64);
            if (lane >= off) sB += n;
        }
        const float TP2 = __shfl(sB, 15, 64);
        const float exB = sB - lsB;

        const float total1 = TP1 + TP2;
        if (lane == 0)
            __hip_atomic_store(&W1[chain + k], pack_av(total1), __ATOMIC_RELAXED,
                               __HIP_MEMORY_SCOPE_AGENT);
        // ---- lookback 1 (single slice: k <= 49) ----
        float carry1 = 0.f;
        {
            float v = 0.f;
            if (lane < k) v = spin_load(&W1[chain + lane]);
            #pragma unroll
            for (int m = 1; m < 64; m <<= 1) v += __shfl_xor(v, m, 64);
            carry1 = v;
        }

        // ---- means + s2, pass1 ----
        const float t0A = (float)(k * TCH + lane * 4);
        f32x4 cntA;
        cntA.x = Cf * (t0A + 1.f); cntA.y = Cf * (t0A + 2.f);
        cntA.z = Cf * (t0A + 3.f); cntA.w = Cf * (t0A + 4.f);
        f32x4 csA;
        csA.x = carry1 + exA + a0; csA.y = carry1 + exA + a1;
        csA.z = carry1 + exA + a2; csA.w = carry1 + exA + a3;
        const f32x4 mnA = csA / cntA;
        mean_l[lane] = mnA;
        const f32x4 s2A = qvA - 2.f * mnA * svA + Cf * mnA * mnA;

        // ---- means + s2, pass2 ----
        const float t0B = (float)(k * TCH + 256 + lane * 4);
        f32x4 cntB;
        cntB.x = Cf * (t0B + 1.f); cntB.y = Cf * (t0B + 2.f);
        cntB.z = Cf * (t0B + 3.f); cntB.w = Cf * (t0B + 4.f);
        f32x4 mnB = 0, s2B = 0;
        if (lane < 16) {
            f32x4 csB;
            const float baseB = carry1 + TP1 + exB;
            csB.x = baseB + e0; csB.y = baseB + e1; csB.z = baseB + e2; csB.w = baseB + e3;
            mnB = csB / cntB;
            mean_l[64 + lane] = mnB;
            s2B = qvB - 2.f * mnB * svB + Cf * mnB * mnB;
        }

        // ---- s2 scan, pass1 ----
        const float d0 = s2A.x, d1 = d0 + s2A.y, d2 = d1 + s2A.z, d3 = d2 + s2A.w;
        float uA = d3;
        #pragma unroll
        for (int off = 1; off < 64; off <<= 1) {
            const float n = __shfl_up(uA, off, 64);
            if (lane >= off) uA += n;
        }
        const float SP1 = __shfl(uA, 63, 64);
        const float ex2A = uA - d3;
        // ---- s2 scan, pass2 ----
        const float f0 = s2B.x, f1 = f0 + s2B.y, f2 = f1 + s2B.z, f3 = f2 + s2B.w;
        float uB = (lane < 16) ? f3 : 0.f;
        const float luB = uB;
        #pragma unroll
        for (int off = 1; off < 16; off <<= 1) {
            const float n = __shfl_up(uB, off, 64);
            if (lane >= off) uB += n;
        }
        const float SP2 = __shfl(uB, 15, 64);
        const float ex2B = uB - luB;

        const float total2 = SP1 + SP2;
        if (lane == 0)
            __hip_atomic_store(&W2[chain + k], pack_av(total2), __ATOMIC_RELAXED,
                               __HIP_MEMORY_SCOPE_AGENT);
        // ---- lookback 2 (single slice) ----
        float carry2 = 0.f;
        {
            float v = 0.f;
            if (lane < k) v = spin_load(&W2[chain + lane]);
            #pragma unroll
            for (int m = 1; m < 64; m <<= 1) v += __shfl_xor(v, m, 64);
            carry2 = v;
        }

        // ---- istd ----
        {
            f32x4 cv;
            cv.x = carry2 + ex2A + d0; cv.y = carry2 + ex2A + d1;
            cv.z = carry2 + ex2A + d2; cv.w = carry2 + ex2A + d3;
            const f32x4 var = cv / cntA;
            f32x4 is;
            is.x = rsqrtf(var.x + EPSF); is.y = rsqrtf(var.y + EPSF);
            is.z = rsqrtf(var.z + EPSF); is.w = rsqrtf(var.w + EPSF);
            istd_l[lane] = is;
        }
        if (lane < 16) {
            f32x4 cv;
            const float base2 = carry2 + SP1 + ex2B;
            cv.x = base2 + f0; cv.y = base2 + f1; cv.z = base2 + f2; cv.w = base2 + f3;
            const f32x4 var = cv / cntB;
            f32x4 is;
            is.x = rsqrtf(var.x + EPSF); is.y = rsqrtf(var.y + EPSF);
            is.z = rsqrtf(var.z + EPSF); is.w = rsqrtf(var.w + EPSF);
            istd_l[64 + lane] = is;
        }
    }
    __syncthreads();

    // ---------- phase C: re-read tile (L3 capacity-hit), normalize, nt-store ----------
    f32x4* ob = (f32x4*)out + (size_t)(b * Cc + c_sub) * T4 + k * T4CH + t4s;
    #pragma unroll
    for (int r = 0; r < 16; ++r) {
        const int c = c_sub + 32 * r;
        const float gc = gam[c];
        const float bc = bet[c];
        #pragma unroll
        for (int g = 0; g < 5; ++g) {
            const int p = g * 16 + t4s;
            const f32x4 m4 = mean_l[p];
            const f32x4 sg = istd_l[p] * gc;
            const f32x4 xv = xbase[(size_t)(32 * r) * T4 + 16 * g];
            __builtin_nontemporal_store(xv * sg + (bc - m4 * sg),
                                        &ob[(size_t)(32 * r) * T4 + 16 * g]);
        }
    }
}

extern "C" void kernel_launch(void* const* d_in, const int* in_sizes, int n_in,
                              void* d_out, int out_size, void* d_ws, size_t ws_size,
                              hipStream_t stream) {
    const float* x     = (const float*)d_in[0];
    const float* gamma = (const float*)d_in[1];
    const float* beta  = (const float*)d_in[2];
    float* out = (float*)d_out;

    unsigned long long* W1 = (unsigned long long*)d_ws;
    unsigned long long* W2 = W1 + (size_t)Bb * NCHK;

    // clear lookback state every launch (ws is NOT re-poisoned between replays)
    hipMemsetAsync(d_ws, 0, 2 * (size_t)Bb * NCHK * sizeof(unsigned long long), stream);

    fused_cln_kernel<<<Bb * NCHK, 512, 0, stream>>>(x, gamma, beta, out, W1, W2);
}

// Round 13
// 175.898 us; speedup vs baseline: 1.3143x; 1.3143x over previous
//
#include <hip/hip_runtime.h>
#include <hip/hip_bf16.h>

// CumulativeLayerNorm fused single-pass v13: x [B=8, C=512, T=16000] f32.
// TCH=320 => 50 chunks/batch, 400 blocks x 1024 thr — ALL co-resident, so
// phase A (stream x, column sums) completes globally at HBM rate, every block
// publishes its aggregate at ~the same instant (spins last only the jitter),
// then phase C re-reads the tile (L3-hot, within-kernel) and nt-stores out.
// Geometry fixes R12's fatal flaw: wave w owns channel group {w+16r}, lane =
// t-position => only TWO accumulator pairs/thread (16 VGPR), plain
// __launch_bounds__(1024) so the compiler can batch loads (R5-style VGPR~56).
// Lookback chains = 50 < 64 => ONE 64-lane slice, no loop.
// Workspace: W1[B*50] + W2[B*50] u64 {flag|f32} (memset 0 each launch).

constexpr int Bb = 8;
constexpr int Cc = 512;
constexpr int Tt = 16000;
constexpr int T4 = Tt / 4;          // 4000
constexpr int TCH = 320;            // t per chunk
constexpr int T4CH = TCH / 4;       // 80 f32x4 positions per chunk
constexpr int NCHK = Tt / TCH;      // 50
constexpr float EPSF = 1e-8f;

typedef float f32x4 __attribute__((ext_vector_type(4)));

__device__ __forceinline__ unsigned long long pack_av(float v) {
    return (1ull << 32) | (unsigned long long)__float_as_uint(v);
}

__device__ __forceinline__ float spin_load(const unsigned long long* p) {
    unsigned long long w;
    for (;;) {
        w = __hip_atomic_load(p, __ATOMIC_RELAXED, __HIP_MEMORY_SCOPE_AGENT);
        if (w >> 32) break;
        __builtin_amdgcn_s_sleep(1);
    }
    return __uint_as_float((unsigned)w);
}

__global__ __launch_bounds__(1024)
void fused_cln_kernel(const float* __restrict__ x,
                      const float* __restrict__ gamma,
                      const float* __restrict__ beta,
                      float* __restrict__ out,
                      unsigned long long* __restrict__ W1,
                      unsigned long long* __restrict__ W2)
{
    const int bid = blockIdx.x;
    const int k = bid >> 3;          // chunk 0..49 (k-major: chains advance together)
    const int b = bid & 7;
    const int tid = threadIdx.x;
    const int lane = tid & 63;       // t4-position within pass
    const int wave = tid >> 6;       // 0..15 = channel group (c = wave + 16r)
    const float Cf = (float)Cc;

    __shared__ f32x4 red_s[16][T4CH], red_q[16][T4CH];   // 40 KB
    __shared__ f32x4 mean_l[T4CH], istd_l[T4CH];         // 2.5 KB
    __shared__ float gam[Cc], bet[Cc];                   // 4 KB

    if (tid < Cc) { gam[tid] = gamma[tid]; bet[tid] = beta[tid]; }

    const f32x4* xrow = (const f32x4*)x + (size_t)(b * Cc + wave) * T4 + k * T4CH;

    // ---------- phase A: stream tile (1 KB/wave/instr), 2 accumulator pairs ----------
    f32x4 ps0 = 0, pq0 = 0, ps1 = 0, pq1 = 0;
    #pragma unroll
    for (int r = 0; r < 32; ++r) {
        const f32x4 v = xrow[(size_t)(16 * r) * T4 + lane];         // pos = lane
        ps0 += v; pq0 += v * v;
        if (lane < 16) {                                            // pos = 64+lane
            const f32x4 u = xrow[(size_t)(16 * r) * T4 + 64 + lane];
            ps1 += u; pq1 += u * u;
        }
    }
    red_s[wave][lane] = ps0;
    red_q[wave][lane] = pq0;
    if (lane < 16) { red_s[wave][64 + lane] = ps1; red_q[wave][64 + lane] = pq1; }
    __syncthreads();

    // ---------- phase B: wave 0 — scan 320 t's (2 passes) + 1-slice lookbacks ----------
    if (tid < 64) {
        const int chain = b * NCHK;

        f32x4 svA = 0, qvA = 0, svB = 0, qvB = 0;
        #pragma unroll
        for (int w = 0; w < 16; ++w) { svA += red_s[w][lane]; qvA += red_q[w][lane]; }
        if (lane < 16) {
            #pragma unroll
            for (int w = 0; w < 16; ++w) { svB += red_s[w][64 + lane]; qvB += red_q[w][64 + lane]; }
        }

        // ---- s1 scan, pass1 (positions 0..63) ----
        const float a0 = svA.x, a1 = a0 + svA.y, a2 = a1 + svA.z, a3 = a2 + svA.w;
        float sA = a3;
        #pragma unroll
        for (int off = 1; off < 64; off <<= 1) {
            const float n = __shfl_up(sA, off, 64);
            if (lane >= off) sA += n;
        }
        const float TP1 = __shfl(sA, 63, 64);
        const float exA = sA - a3;
        // ---- s1 scan, pass2 (positions 64..79, lanes 0..15) ----
        const float e0 = svB.x, e1 = e0 + svB.y, e2 = e1 + svB.z, e3 = e2 + svB.w;
        float sB = (lane < 16) ? e3 : 0.f;
        const float lsB = sB;
        #pragma unroll
        for (int off = 1; off < 16; off <<= 1) {
            const float n = __shfl_up(sB, off, 64);
            if (lane >= off) sB += n;
        }
        const float TP2 = __shfl(sB, 15, 64);
        const float exB = sB - lsB;

        if (lane == 0)
            __hip_atomic_store(&W1[chain + k], pack_av(TP1 + TP2), __ATOMIC_RELAXED,
                               __HIP_MEMORY_SCOPE_AGENT);
        // ---- lookback 1 (single slice: k <= 49) ----
        float carry1;
        {
            float v = 0.f;
            if (lane < k) v = spin_load(&W1[chain + lane]);
            #pragma unroll
            for (int m = 1; m < 64; m <<= 1) v += __shfl_xor(v, m, 64);
            carry1 = v;
        }

        // ---- means + s2, pass1 ----
        const float t0A = (float)(k * TCH + lane * 4);
        f32x4 cntA;
        cntA.x = Cf * (t0A + 1.f); cntA.y = Cf * (t0A + 2.f);
        cntA.z = Cf * (t0A + 3.f); cntA.w = Cf * (t0A + 4.f);
        f32x4 csA;
        csA.x = carry1 + exA + a0; csA.y = carry1 + exA + a1;
        csA.z = carry1 + exA + a2; csA.w = carry1 + exA + a3;
        const f32x4 mnA = csA / cntA;
        mean_l[lane] = mnA;
        const f32x4 s2A = qvA - 2.f * mnA * svA + Cf * mnA * mnA;

        // ---- means + s2, pass2 ----
        const float t0B = (float)(k * TCH + 256 + lane * 4);
        f32x4 cntB;
        cntB.x = Cf * (t0B + 1.f); cntB.y = Cf * (t0B + 2.f);
        cntB.z = Cf * (t0B + 3.f); cntB.w = Cf * (t0B + 4.f);
        f32x4 mnB = 0, s2B = 0;
        if (lane < 16) {
            const float baseB = carry1 + TP1 + exB;
            f32x4 csB;
            csB.x = baseB + e0; csB.y = baseB + e1; csB.z = baseB + e2; csB.w = baseB + e3;
            mnB = csB / cntB;
            mean_l[64 + lane] = mnB;
            s2B = qvB - 2.f * mnB * svB + Cf * mnB * mnB;
        }

        // ---- s2 scan, pass1 ----
        const float d0 = s2A.x, d1 = d0 + s2A.y, d2 = d1 + s2A.z, d3 = d2 + s2A.w;
        float uA = d3;
        #pragma unroll
        for (int off = 1; off < 64; off <<= 1) {
            const float n = __shfl_up(uA, off, 64);
            if (lane >= off) uA += n;
        }
        const float SP1 = __shfl(uA, 63, 64);
        const float ex2A = uA - d3;
        // ---- s2 scan, pass2 ----
        const float f0 = s2B.x, f1 = f0 + s2B.y, f2 = f1 + s2B.z, f3 = f2 + s2B.w;
        float uB = (lane < 16) ? f3 : 0.f;
        const float luB = uB;
        #pragma unroll
        for (int off = 1; off < 16; off <<= 1) {
            const float n = __shfl_up(uB, off, 64);
            if (lane >= off) uB += n;
        }
        const float SP2 = __shfl(uB, 15, 64);
        const float ex2B = uB - luB;

        if (lane == 0)
            __hip_atomic_store(&W2[chain + k], pack_av(SP1 + SP2), __ATOMIC_RELAXED,
                               __HIP_MEMORY_SCOPE_AGENT);
        // ---- lookback 2 (single slice) ----
        float carry2;
        {
            float v = 0.f;
            if (lane < k) v = spin_load(&W2[chain + lane]);
            #pragma unroll
            for (int m = 1; m < 64; m <<= 1) v += __shfl_xor(v, m, 64);
            carry2 = v;
        }

        // ---- istd ----
        {
            f32x4 cv;
            cv.x = carry2 + ex2A + d0; cv.y = carry2 + ex2A + d1;
            cv.z = carry2 + ex2A + d2; cv.w = carry2 + ex2A + d3;
            const f32x4 var = cv / cntA;
            f32x4 is;
            is.x = rsqrtf(var.x + EPSF); is.y = rsqrtf(var.y + EPSF);
            is.z = rsqrtf(var.z + EPSF); is.w = rsqrtf(var.w + EPSF);
            istd_l[lane] = is;
        }
        if (lane < 16) {
            const float base2 = carry2 + SP1 + ex2B;
            f32x4 cv;
            cv.x = base2 + f0; cv.y = base2 + f1; cv.z = base2 + f2; cv.w = base2 + f3;
            const f32x4 var = cv / cntB;
            f32x4 is;
            is.x = rsqrtf(var.x + EPSF); is.y = rsqrtf(var.y + EPSF);
            is.z = rsqrtf(var.z + EPSF); is.w = rsqrtf(var.w + EPSF);
            istd_l[64 + lane] = is;
        }
    }
    __syncthreads();

    // ---------- phase C: re-read tile (L3-hot), normalize, nt-store ----------
    const f32x4 m0 = mean_l[lane];
    const f32x4 s0 = istd_l[lane];
    f32x4 m1 = 0, s1v = 0;
    if (lane < 16) { m1 = mean_l[64 + lane]; s1v = istd_l[64 + lane]; }

    f32x4* orow = (f32x4*)out + (size_t)(b * Cc + wave) * T4 + k * T4CH;
    #pragma unroll
    for (int r = 0; r < 32; ++r) {
        const int c = wave + 16 * r;
        const float gc = gam[c];
        const float bc = bet[c];
        {
            const f32x4 sg = s0 * gc;
            const f32x4 v = xrow[(size_t)(16 * r) * T4 + lane];
            __builtin_nontemporal_store(v * sg + (bc - m0 * sg),
                                        &orow[(size_t)(16 * r) * T4 + lane]);
        }
        if (lane < 16) {
            const f32x4 sg = s1v * gc;
            const f32x4 u = xrow[(size_t)(16 * r) * T4 + 64 + lane];
            __builtin_nontemporal_store(u * sg + (bc - m1 * sg),
                                        &orow[(size_t)(16 * r) * T4 + 64 + lane]);
        }
    }
}

extern "C" void kernel_launch(void* const* d_in, const int* in_sizes, int n_in,
                              void* d_out, int out_size, void* d_ws, size_t ws_size,
                              hipStream_t stream) {
    const float* x     = (const float*)d_in[0];
    const float* gamma = (const float*)d_in[1];
    const float* beta  = (const float*)d_in[2];
    float* out = (float*)d_out;

    unsigned long long* W1 = (unsigned long long*)d_ws;
    unsigned long long* W2 = W1 + (size_t)Bb * NCHK;

    // clear lookback state every launch (ws is NOT re-poisoned between replays)
    hipMemsetAsync(d_ws, 0, 2 * (size_t)Bb * NCHK * sizeof(unsigned long long), stream);

    fused_cln_kernel<<<Bb * NCHK, 1024, 0, stream>>>(x, gamma, beta, out, W1, W2);
}